// Round 1
// baseline (250.889 us; speedup 1.0000x reference)
//
#include <hip/hip_runtime.h>
#include <hip/hip_bf16.h>

#define DEVFN __device__ __forceinline__

typedef float f32x4 __attribute__((ext_vector_type(4)));
typedef __bf16 bf16x8 __attribute__((ext_vector_type(8)));
typedef unsigned short u16x8 __attribute__((ext_vector_type(8)));
typedef unsigned short u16x4 __attribute__((ext_vector_type(4)));

DEVFN unsigned short f2bf(float f) {
  unsigned u = __builtin_bit_cast(unsigned, f);
  u = (u + 0x7FFFu + ((u >> 16) & 1u)) >> 16;  // RNE
  return (unsigned short)u;
}

DEVFN f32x4 mfma_bf16(u16x8 a, u16x8 b, f32x4 c) {
  return __builtin_amdgcn_mfma_f32_16x16x32_bf16((bf16x8)a, (bf16x8)b, c, 0, 0, 0);
}

DEVFN void gload_lds16(const void* g, void* l) {
  __builtin_amdgcn_global_load_lds(
      (const __attribute__((address_space(1))) void*)g,
      (__attribute__((address_space(3))) void*)l, 16, 0, 0);
}

// ---------- 1. LayerNorm on strided rows -> xs bf16 [B*Ts][D] ----------
__global__ __launch_bounds__(256) void ln_stride_kernel(
    const float* __restrict__ x, const float* __restrict__ w,
    const float* __restrict__ bb, unsigned short* __restrict__ xs,
    int T, int Ts, int D, int stride) {
  int row = blockIdx.x;  // B*Ts rows
  int b = row / Ts, ts = row - b * Ts;
  const float* xr = x + ((size_t)b * T + (size_t)ts * stride) * D;
  int t = threadIdx.x;
  float4 v = *(const float4*)(xr + t * 4);
  float s = v.x + v.y + v.z + v.w;
  float sq = v.x * v.x + v.y * v.y + v.z * v.z + v.w * v.w;
#pragma unroll
  for (int m = 1; m < 64; m <<= 1) { s += __shfl_xor(s, m); sq += __shfl_xor(sq, m); }
  __shared__ float ps[4], pq[4];
  if ((t & 63) == 0) { ps[t >> 6] = s; pq[t >> 6] = sq; }
  __syncthreads();
  s = ps[0] + ps[1] + ps[2] + ps[3];
  sq = pq[0] + pq[1] + pq[2] + pq[3];
  float invD = 1.0f / (float)D;
  float mu = s * invD;
  float var = sq * invD - mu * mu;
  float rs = rsqrtf(var + 1e-5f);
  int c = t * 4;
  float4 wv = *(const float4*)(w + c);
  float4 bv = *(const float4*)(bb + c);
  u16x4 o;
  o[0] = f2bf((v.x - mu) * rs * wv.x + bv.x);
  o[1] = f2bf((v.y - mu) * rs * wv.y + bv.y);
  o[2] = f2bf((v.z - mu) * rs * wv.z + bv.z);
  o[3] = f2bf((v.w - mu) * rs * wv.w + bv.w);
  *(u16x4*)(xs + (size_t)row * D + c) = o;
}

// ---------- 2. W [K][N] f32 -> Wt [N][K] bf16 ----------
__global__ __launch_bounds__(256) void wconv_kernel(
    const float* __restrict__ W, unsigned short* __restrict__ Wt, int K, int N) {
  __shared__ float tile[32][33];
  int n0 = blockIdx.x * 32, k0 = blockIdx.y * 32;
  int tx = threadIdx.x & 31, ty = threadIdx.x >> 5;
#pragma unroll
  for (int i = 0; i < 32; i += 8) tile[ty + i][tx] = W[(size_t)(k0 + ty + i) * N + n0 + tx];
  __syncthreads();
#pragma unroll
  for (int i = 0; i < 32; i += 8) Wt[(size_t)(n0 + ty + i) * K + k0 + tx] = f2bf(tile[tx][ty + i]);
}

// ---------- 3/5. GEMM: A[M][K] bf16 x Bt[N][K] bf16 ----------
// MODE 0: QKV epilogue (bias + RoPE, scatter to Q,K [B,H,Ts,64] and Vt [B,H,64,Ts])
// MODE 1: plain epilogue (bias, f32 out [M][N])
template <int MODE>
__global__ __launch_bounds__(256) void gemm_kernel(
    const unsigned short* __restrict__ A, const unsigned short* __restrict__ Bt,
    const float* __restrict__ bias, int M, int N, int Kd,
    unsigned short* __restrict__ Qo, unsigned short* __restrict__ Ko,
    unsigned short* __restrict__ Vt, float* __restrict__ Co) {
  constexpr int BK = 32;
  __shared__ unsigned short As[128 * BK];
  __shared__ unsigned short Bs[128 * BK];
  int nbm = M >> 7;
  int bm = blockIdx.x % nbm, bn = blockIdx.x / nbm;
  int m0 = bm << 7, n0 = bn << 7;
  int t = threadIdx.x, l = t & 63, w = t >> 6;
  int wr = w >> 1, wc = w & 1;
  int lg = l >> 4, lr = l & 15;

  f32x4 acc[4][4] = {};
  int srow = t >> 2, scol = (t & 3) * 8;
  const unsigned short* gA = A + (size_t)(m0 + srow) * Kd + scol;
  const unsigned short* gB = Bt + (size_t)(n0 + srow) * Kd + scol;
  unsigned short* lA = As + t * 8;
  unsigned short* lB = Bs + t * 8;

  for (int k0 = 0; k0 < Kd; k0 += BK) {
    gload_lds16(gA + k0, lA);
    gload_lds16(gA + k0 + (size_t)64 * Kd, lA + 64 * BK);
    gload_lds16(gB + k0, lB);
    gload_lds16(gB + k0 + (size_t)64 * Kd, lB + 64 * BK);
    __syncthreads();
    u16x8 af[4], bf[4];
#pragma unroll
    for (int i = 0; i < 4; i++) {
      af[i] = *(const u16x8*)(As + (wr * 64 + i * 16 + lr) * BK + lg * 8);
      bf[i] = *(const u16x8*)(Bs + (wc * 64 + i * 16 + lr) * BK + lg * 8);
    }
#pragma unroll
    for (int i = 0; i < 4; i++)
#pragma unroll
      for (int j = 0; j < 4; j++) acc[i][j] = mfma_bf16(af[i], bf[j], acc[i][j]);
    __syncthreads();
  }

  if constexpr (MODE == 0) {
    int nb = n0 + wc * 64;       // 64-aligned -> exactly one (which, head)
    int which = nb >> 10;        // 0=q 1=k 2=v
    int h = (nb & 1023) >> 6;
    if (which < 2) {
      unsigned short* dst = (which == 0) ? Qo : Ko;
#pragma unroll
      for (int nt = 0; nt < 2; nt++) {
        int d = nt * 16 + lr;  // 0..31, pairs with d+32 at nt+2
        float invf = powf(10000.0f, -(float)d * (1.0f / 32.0f));
        float blo = bias[nb + nt * 16 + lr];
        float bhi = bias[nb + (nt + 2) * 16 + lr];
#pragma unroll
        for (int mt = 0; mt < 4; mt++) {
          int mb = m0 + wr * 64 + mt * 16 + lg * 4;
#pragma unroll
          for (int r = 0; r < 4; r++) {
            int m = mb + r;
            int b_ = m >> 10, ts = m & 1023;
            float va = acc[mt][nt][r] + blo;
            float vb = acc[mt][nt + 2][r] + bhi;
            float ang = (float)ts * invf;
            float sn, cs;
            sincosf(ang, &sn, &cs);
            size_t base = (((size_t)(b_ * 16 + h)) * 1024 + ts) * 64;
            dst[base + d] = f2bf(va * cs - vb * sn);
            dst[base + d + 32] = f2bf(vb * cs + va * sn);
          }
        }
      }
    } else {
#pragma unroll
      for (int nt = 0; nt < 4; nt++) {
        int d = nt * 16 + lr;
        float bi = bias[nb + nt * 16 + lr];
#pragma unroll
        for (int mt = 0; mt < 4; mt++) {
          int mb = m0 + wr * 64 + mt * 16 + lg * 4;
          int b_ = mb >> 10, tsb = mb & 1023;
          u16x4 pk;
#pragma unroll
          for (int r = 0; r < 4; r++) pk[r] = f2bf(acc[mt][nt][r] + bi);
          *(u16x4*)(Vt + ((size_t)(b_ * 16 + h) * 64 + d) * 1024 + tsb) = pk;
        }
      }
    }
  } else {
#pragma unroll
    for (int nt = 0; nt < 4; nt++) {
      int n = n0 + wc * 64 + nt * 16 + lr;
      float bi = bias[n];
#pragma unroll
      for (int mt = 0; mt < 4; mt++) {
        int mb = m0 + wr * 64 + mt * 16 + lg * 4;
#pragma unroll
        for (int r = 0; r < 4; r++) Co[(size_t)(mb + r) * N + n] = acc[mt][nt][r] + bi;
      }
    }
  }
}

// ---------- 4. causal flash attention ----------
// Q,K: [B,H,Ts,64] bf16 ; Vt: [B,H,64,Ts] bf16 ; O: [B,Ts,H*64] bf16
__global__ __launch_bounds__(256) void attn_kernel(
    const unsigned short* __restrict__ Q, const unsigned short* __restrict__ K,
    const unsigned short* __restrict__ Vt, unsigned short* __restrict__ O,
    int Ts, int H) {
  int nq = Ts >> 6;
  int qb = blockIdx.x % nq;
  int hh = (blockIdx.x / nq) % H;
  int b = blockIdx.x / (nq * H);
  int t = threadIdx.x, l = t & 63, w = t >> 6;
  int lg = l >> 4, lr = l & 15;
  int q0 = qb * 64 + w * 16;  // this wave's 16 q rows
  const unsigned short* Qh = Q + ((size_t)(b * H + hh) * Ts) * 64;
  const unsigned short* Kh = K + ((size_t)(b * H + hh) * Ts) * 64;
  const unsigned short* Vh = Vt + ((size_t)(b * H + hh) * 64) * Ts;

  __shared__ unsigned short Pl[4][16 * 32];  // per-wave P buffer
  unsigned short* Pw = Pl[w];

  u16x8 aQ0 = *(const u16x8*)(Qh + (size_t)(q0 + lr) * 64 + lg * 8);
  u16x8 aQ1 = *(const u16x8*)(Qh + (size_t)(q0 + lr) * 64 + 32 + lg * 8);

  f32x4 o[4] = {};
  float mrow[4] = {-1e30f, -1e30f, -1e30f, -1e30f};
  float lsum[4] = {0.f, 0.f, 0.f, 0.f};

  int kv_end = q0 + 16;
  for (int kv0 = 0; kv0 < kv_end; kv0 += 32) {
    f32x4 s0, s1;
    {
      u16x8 k0a = *(const u16x8*)(Kh + (size_t)(kv0 + lr) * 64 + lg * 8);
      u16x8 k0b = *(const u16x8*)(Kh + (size_t)(kv0 + lr) * 64 + 32 + lg * 8);
      f32x4 z = {};
      z = mfma_bf16(aQ0, k0a, z);
      s0 = mfma_bf16(aQ1, k0b, z);
      u16x8 k1a = *(const u16x8*)(Kh + (size_t)(kv0 + 16 + lr) * 64 + lg * 8);
      u16x8 k1b = *(const u16x8*)(Kh + (size_t)(kv0 + 16 + lr) * 64 + 32 + lg * 8);
      f32x4 z2 = {};
      z2 = mfma_bf16(aQ0, k1a, z2);
      s1 = mfma_bf16(aQ1, k1b, z2);
    }
    bool needmask = (kv0 + 31 > q0);
#pragma unroll
    for (int r = 0; r < 4; r++) {
      int qi = q0 + lg * 4 + r;
      float v0 = s0[r] * 0.125f, v1 = s1[r] * 0.125f;
      if (needmask) {
        if (kv0 + lr > qi) v0 = -1e30f;
        if (kv0 + 16 + lr > qi) v1 = -1e30f;
      }
      float mx = fmaxf(v0, v1);
#pragma unroll
      for (int mm = 1; mm < 16; mm <<= 1) mx = fmaxf(mx, __shfl_xor(mx, mm));
      float mnew = fmaxf(mrow[r], mx);
      float p0 = __expf(v0 - mnew);
      float p1 = __expf(v1 - mnew);
      float al = __expf(mrow[r] - mnew);
      mrow[r] = mnew;
      float psum = p0 + p1;
#pragma unroll
      for (int mm = 1; mm < 16; mm <<= 1) psum += __shfl_xor(psum, mm);
      lsum[r] = lsum[r] * al + psum;
      Pw[(lg * 4 + r) * 32 + lr] = f2bf(p0);
      Pw[(lg * 4 + r) * 32 + 16 + lr] = f2bf(p1);
      o[0][r] *= al; o[1][r] *= al; o[2][r] *= al; o[3][r] *= al;
    }
    // re-layout P via per-wave LDS (compiler orders ds_write -> ds_read)
    u16x8 aP = *(const u16x8*)(Pw + lr * 32 + lg * 8);
#pragma unroll
    for (int nt = 0; nt < 4; nt++) {
      u16x8 bV = *(const u16x8*)(Vh + (size_t)(nt * 16 + lr) * Ts + kv0 + lg * 8);
      o[nt] = mfma_bf16(aP, bV, o[nt]);
    }
  }
#pragma unroll
  for (int r = 0; r < 4; r++) {
    float inv = 1.0f / lsum[r];
    int ts = q0 + lg * 4 + r;
    size_t base = ((size_t)b * Ts + ts) * (size_t)(H * 64) + hh * 64;
#pragma unroll
    for (int nt = 0; nt < 4; nt++) O[base + nt * 16 + lr] = f2bf(o[nt][r] * inv);
  }
}

// ---------- 6. upsample + residual ----------
__global__ __launch_bounds__(256) void upsample_kernel(
    const float* __restrict__ x, const float* __restrict__ proj,
    float* __restrict__ out, int T, int Ts, int D) {
  size_t g = (size_t)blockIdx.x * 256 + threadIdx.x;
  int dq = D >> 2;
  int d4 = (int)(g % dq);
  size_t bt = g / dq;
  int tt = (int)(bt % T);
  int b = (int)(bt / T);
  float src = ((float)tt + 0.5f) * ((float)Ts / (float)T) - 0.5f;
  src = fminf(fmaxf(src, 0.0f), (float)(Ts - 1));
  int i0 = (int)src;  // src >= 0 -> trunc == floor
  int i1 = min(i0 + 1, Ts - 1);
  float wg = src - (float)i0;
  const float4 xv = *(const float4*)(x + ((size_t)b * T + tt) * D + d4 * 4);
  const float4 p0 = *(const float4*)(proj + ((size_t)b * Ts + i0) * D + d4 * 4);
  const float4 p1 = *(const float4*)(proj + ((size_t)b * Ts + i1) * D + d4 * 4);
  float4 ov;
  ov.x = xv.x + p0.x * (1.0f - wg) + p1.x * wg;
  ov.y = xv.y + p0.y * (1.0f - wg) + p1.y * wg;
  ov.z = xv.z + p0.z * (1.0f - wg) + p1.z * wg;
  ov.w = xv.w + p0.w * (1.0f - wg) + p1.w * wg;
  *(float4*)(out + ((size_t)b * T + tt) * D + d4 * 4) = ov;
}

extern "C" void kernel_launch(void* const* d_in, const int* in_sizes, int n_in,
                              void* d_out, int out_size, void* d_ws, size_t ws_size,
                              hipStream_t stream) {
  (void)in_sizes; (void)n_in; (void)out_size; (void)ws_size;
  const float* x = (const float*)d_in[0];
  const float* norm_w = (const float*)d_in[1];
  const float* norm_b = (const float*)d_in[2];
  const float* W_qkv = (const float*)d_in[3];
  const float* b_qkv = (const float*)d_in[4];
  const float* W_out = (const float*)d_in[5];
  const float* b_out = (const float*)d_in[6];
  float* out = (float*)d_out;

  const int B = 4, T = 4096, D = 1024, H = 16, STR = 4;
  const int Ts = T / STR;   // 1024
  const int M = B * Ts;     // 4096

  char* ws = (char*)d_ws;
  unsigned short* xs  = (unsigned short*)(ws);                      // 8 MiB, reused as att_out
  unsigned short* Wtq = (unsigned short*)(ws + ((size_t)8 << 20));  // 6 MiB
  unsigned short* Wto = (unsigned short*)(ws + ((size_t)14 << 20)); // 2 MiB
  unsigned short* Qb  = (unsigned short*)(ws + ((size_t)16 << 20)); // 8 MiB
  unsigned short* Kb  = (unsigned short*)(ws + ((size_t)24 << 20)); // 8 MiB
  unsigned short* Vtb = (unsigned short*)(ws + ((size_t)32 << 20)); // 8 MiB
  float* proj         = (float*)(ws + ((size_t)16 << 20));          // 16 MiB, overlays Q/K (dead)
  unsigned short* att = xs;                                         // overlays xs (dead)

  ln_stride_kernel<<<M, 256, 0, stream>>>(x, norm_w, norm_b, xs, T, Ts, D, STR);
  wconv_kernel<<<dim3(3 * D / 32, D / 32), 256, 0, stream>>>(W_qkv, Wtq, D, 3 * D);
  wconv_kernel<<<dim3(D / 32, D / 32), 256, 0, stream>>>(W_out, Wto, D, D);
  gemm_kernel<0><<<(M / 128) * (3 * D / 128), 256, 0, stream>>>(
      xs, Wtq, b_qkv, M, 3 * D, D, Qb, Kb, Vtb, nullptr);
  attn_kernel<<<B * H * (Ts / 64), 256, 0, stream>>>(Qb, Kb, Vtb, att, Ts, H);
  gemm_kernel<1><<<(M / 128) * (D / 128), 256, 0, stream>>>(
      att, Wto, b_out, M, D, D, nullptr, nullptr, nullptr, proj);
  upsample_kernel<<<(B * T * (D / 4)) / 256, 256, 0, stream>>>(x, proj, out, T, Ts, D);
}

// Round 2
// 197.366 us; speedup vs baseline: 1.2712x; 1.2712x over previous
//
#include <hip/hip_runtime.h>
#include <hip/hip_bf16.h>

#define DEVFN __device__ __forceinline__

typedef float f32x4 __attribute__((ext_vector_type(4)));
typedef float f32x16 __attribute__((ext_vector_type(16)));
typedef __bf16 bf16x8 __attribute__((ext_vector_type(8)));
typedef unsigned short u16x8 __attribute__((ext_vector_type(8)));
typedef unsigned short u16x4 __attribute__((ext_vector_type(4)));
typedef unsigned u32x4 __attribute__((ext_vector_type(4)));

DEVFN unsigned short f2bf(float f) {
  unsigned u = __builtin_bit_cast(unsigned, f);
  u = (u + 0x7FFFu + ((u >> 16) & 1u)) >> 16;  // RNE
  return (unsigned short)u;
}

DEVFN f32x4 mfma_bf16(u16x8 a, u16x8 b, f32x4 c) {
  return __builtin_amdgcn_mfma_f32_16x16x32_bf16((bf16x8)a, (bf16x8)b, c, 0, 0, 0);
}

DEVFN f32x16 mfma32(u16x8 a, u16x8 b, f32x16 c) {
  return __builtin_amdgcn_mfma_f32_32x32x16_bf16((bf16x8)a, (bf16x8)b, c, 0, 0, 0);
}

DEVFN unsigned cvt_pk_bf16(float a, float b) {
  unsigned r;
  asm("v_cvt_pk_bf16_f32 %0, %1, %2" : "=v"(r) : "v"(a), "v"(b));
  return r;  // a in [15:0], b in [31:16]
}

DEVFN void gload_lds16(const void* g, void* l) {
  __builtin_amdgcn_global_load_lds(
      (const __attribute__((address_space(1))) void*)g,
      (__attribute__((address_space(3))) void*)l, 16, 0, 0);
}

// ---------- 1. LayerNorm on strided rows -> xs bf16 [B*Ts][D] ----------
__global__ __launch_bounds__(256) void ln_stride_kernel(
    const float* __restrict__ x, const float* __restrict__ w,
    const float* __restrict__ bb, unsigned short* __restrict__ xs,
    int T, int Ts, int D, int stride) {
  int row = blockIdx.x;  // B*Ts rows
  int b = row / Ts, ts = row - b * Ts;
  const float* xr = x + ((size_t)b * T + (size_t)ts * stride) * D;
  int t = threadIdx.x;
  float4 v = *(const float4*)(xr + t * 4);
  float s = v.x + v.y + v.z + v.w;
  float sq = v.x * v.x + v.y * v.y + v.z * v.z + v.w * v.w;
#pragma unroll
  for (int m = 1; m < 64; m <<= 1) { s += __shfl_xor(s, m); sq += __shfl_xor(sq, m); }
  __shared__ float ps[4], pq[4];
  if ((t & 63) == 0) { ps[t >> 6] = s; pq[t >> 6] = sq; }
  __syncthreads();
  s = ps[0] + ps[1] + ps[2] + ps[3];
  sq = pq[0] + pq[1] + pq[2] + pq[3];
  float invD = 1.0f / (float)D;
  float mu = s * invD;
  float var = sq * invD - mu * mu;
  float rs = rsqrtf(var + 1e-5f);
  int c = t * 4;
  float4 wv = *(const float4*)(w + c);
  float4 bv = *(const float4*)(bb + c);
  u16x4 o;
  o[0] = f2bf((v.x - mu) * rs * wv.x + bv.x);
  o[1] = f2bf((v.y - mu) * rs * wv.y + bv.y);
  o[2] = f2bf((v.z - mu) * rs * wv.z + bv.z);
  o[3] = f2bf((v.w - mu) * rs * wv.w + bv.w);
  *(u16x4*)(xs + (size_t)row * D + c) = o;
}

// ---------- 2. W [K][N] f32 -> Wt [N][K] bf16 ----------
__global__ __launch_bounds__(256) void wconv_kernel(
    const float* __restrict__ W, unsigned short* __restrict__ Wt, int K, int N) {
  __shared__ float tile[32][33];
  int n0 = blockIdx.x * 32, k0 = blockIdx.y * 32;
  int tx = threadIdx.x & 31, ty = threadIdx.x >> 5;
#pragma unroll
  for (int i = 0; i < 32; i += 8) tile[ty + i][tx] = W[(size_t)(k0 + ty + i) * N + n0 + tx];
  __syncthreads();
#pragma unroll
  for (int i = 0; i < 32; i += 8) Wt[(size_t)(n0 + ty + i) * K + k0 + tx] = f2bf(tile[tx][ty + i]);
}

// ---------- 3/5. GEMM: A[M][K] bf16 x Bt[N][K] bf16 ----------
template <int MODE>
__global__ __launch_bounds__(256) void gemm_kernel(
    const unsigned short* __restrict__ A, const unsigned short* __restrict__ Bt,
    const float* __restrict__ bias, int M, int N, int Kd,
    unsigned short* __restrict__ Qo, unsigned short* __restrict__ Ko,
    unsigned short* __restrict__ Vt, float* __restrict__ Co) {
  constexpr int BK = 32;
  __shared__ unsigned short As[128 * BK];
  __shared__ unsigned short Bs[128 * BK];
  int nbm = M >> 7;
  int bm = blockIdx.x % nbm, bn = blockIdx.x / nbm;
  int m0 = bm << 7, n0 = bn << 7;
  int t = threadIdx.x, l = t & 63, w = t >> 6;
  int wr = w >> 1, wc = w & 1;
  int lg = l >> 4, lr = l & 15;

  f32x4 acc[4][4] = {};
  int srow = t >> 2, scol = (t & 3) * 8;
  const unsigned short* gA = A + (size_t)(m0 + srow) * Kd + scol;
  const unsigned short* gB = Bt + (size_t)(n0 + srow) * Kd + scol;
  unsigned short* lA = As + t * 8;
  unsigned short* lB = Bs + t * 8;

  for (int k0 = 0; k0 < Kd; k0 += BK) {
    gload_lds16(gA + k0, lA);
    gload_lds16(gA + k0 + (size_t)64 * Kd, lA + 64 * BK);
    gload_lds16(gB + k0, lB);
    gload_lds16(gB + k0 + (size_t)64 * Kd, lB + 64 * BK);
    __syncthreads();
    u16x8 af[4], bf[4];
#pragma unroll
    for (int i = 0; i < 4; i++) {
      af[i] = *(const u16x8*)(As + (wr * 64 + i * 16 + lr) * BK + lg * 8);
      bf[i] = *(const u16x8*)(Bs + (wc * 64 + i * 16 + lr) * BK + lg * 8);
    }
#pragma unroll
    for (int i = 0; i < 4; i++)
#pragma unroll
      for (int j = 0; j < 4; j++) acc[i][j] = mfma_bf16(af[i], bf[j], acc[i][j]);
    __syncthreads();
  }

  if constexpr (MODE == 0) {
    int nb = n0 + wc * 64;       // 64-aligned -> exactly one (which, head)
    int which = nb >> 10;        // 0=q 1=k 2=v
    int h = (nb & 1023) >> 6;
    if (which < 2) {
      unsigned short* dst = (which == 0) ? Qo : Ko;
#pragma unroll
      for (int nt = 0; nt < 2; nt++) {
        int d = nt * 16 + lr;  // 0..31, pairs with d+32 at nt+2
        float invf = powf(10000.0f, -(float)d * (1.0f / 32.0f));
        float blo = bias[nb + nt * 16 + lr];
        float bhi = bias[nb + (nt + 2) * 16 + lr];
#pragma unroll
        for (int mt = 0; mt < 4; mt++) {
          int mb = m0 + wr * 64 + mt * 16 + lg * 4;
#pragma unroll
          for (int r = 0; r < 4; r++) {
            int m = mb + r;
            int b_ = m >> 10, ts = m & 1023;
            float va = acc[mt][nt][r] + blo;
            float vb = acc[mt][nt + 2][r] + bhi;
            float ang = (float)ts * invf;
            float sn, cs;
            sincosf(ang, &sn, &cs);
            size_t base = (((size_t)(b_ * 16 + h)) * 1024 + ts) * 64;
            dst[base + d] = f2bf(va * cs - vb * sn);
            dst[base + d + 32] = f2bf(vb * cs + va * sn);
          }
        }
      }
    } else {
#pragma unroll
      for (int nt = 0; nt < 4; nt++) {
        int d = nt * 16 + lr;
        float bi = bias[nb + nt * 16 + lr];
#pragma unroll
        for (int mt = 0; mt < 4; mt++) {
          int mb = m0 + wr * 64 + mt * 16 + lg * 4;
          int b_ = mb >> 10, tsb = mb & 1023;
          u16x4 pk;
#pragma unroll
          for (int r = 0; r < 4; r++) pk[r] = f2bf(acc[mt][nt][r] + bi);
          *(u16x4*)(Vt + ((size_t)(b_ * 16 + h) * 64 + d) * 1024 + tsb) = pk;
        }
      }
    }
  } else {
#pragma unroll
    for (int nt = 0; nt < 4; nt++) {
      int n = n0 + wc * 64 + nt * 16 + lr;
      float bi = bias[n];
#pragma unroll
      for (int mt = 0; mt < 4; mt++) {
        int mb = m0 + wr * 64 + mt * 16 + lg * 4;
#pragma unroll
        for (int r = 0; r < 4; r++) Co[(size_t)(mb + r) * N + n] = acc[mt][nt][r] + bi;
      }
    }
  }
}

// ---------- 4. causal flash attention, swapped-operand 32x32x16 ----------
// Q,K: [B,H,Ts,64] bf16 ; Vt: [B,H,64,Ts] bf16 ; O: [B,Ts,H*64] bf16
// One wave = 32 q-rows. S^T = mfma(K,Q): lane owns q-col (l&31) -> scalar m/l state.
// O kept transposed: O^T = mfma(Vt, P^T): lane owns same q-col -> scalar rescale.
__global__ __launch_bounds__(256) void attn_kernel(
    const unsigned short* __restrict__ Q, const unsigned short* __restrict__ K,
    const unsigned short* __restrict__ Vt, unsigned short* __restrict__ O,
    int Ts, int H) {
  int t = threadIdx.x, w = t >> 6, l = t & 63;
  int h2 = l >> 5, lq = l & 31;
  int bh = blockIdx.x >> 3;   // b*H + h
  int qg = blockIdx.x & 7;    // q-group of 128 rows
  int b = bh / H, hh = bh % H;
  int q0 = (qg * 4 + w) * 32; // this wave's 32 q rows

  const unsigned short* Qh = Q + ((size_t)bh * Ts) * 64;
  const unsigned short* Kh = K + ((size_t)bh * Ts) * 64;
  const unsigned short* Vh = Vt + ((size_t)bh * 64) * Ts;

  // Q fragments (B-operand): lane needs Q[q0+lq][c*16 + h2*8 + e]
  u16x8 qf[4];
#pragma unroll
  for (int c = 0; c < 4; c++)
    qf[c] = *(const u16x8*)(Qh + (size_t)(q0 + lq) * 64 + c * 16 + h2 * 8);

  const unsigned short* kb = Kh + (size_t)lq * 64 + h2 * 8;
  const unsigned short* vb = Vh + (size_t)lq * Ts + h2 * 8;

  // preload tile 0
  u16x8 kf[4], vf[4];
#pragma unroll
  for (int c = 0; c < 4; c++) kf[c] = *(const u16x8*)(kb + c * 16);
  vf[0] = *(const u16x8*)(vb);
  vf[1] = *(const u16x8*)(vb + 16);
  vf[2] = *(const u16x8*)(vb + (size_t)32 * Ts);
  vf[3] = *(const u16x8*)(vb + (size_t)32 * Ts + 16);

  f32x16 olo = {}, ohi = {};
  float mrow = -1e30f, lsum = 0.f;
  const float scale2 = 0.18033688f;  // (1/sqrt(64)) * log2(e); softmax in base-2

  for (int kv0 = 0; kv0 <= q0; kv0 += 32) {
    // register prefetch of next K/V tile (hides L2 latency under MFMA+softmax)
    int nkv = (kv0 + 32 <= q0) ? kv0 + 32 : kv0;
    u16x8 kn[4], vn[4];
#pragma unroll
    for (int c = 0; c < 4; c++)
      kn[c] = *(const u16x8*)(kb + (size_t)nkv * 64 + c * 16);
    vn[0] = *(const u16x8*)(vb + nkv);
    vn[1] = *(const u16x8*)(vb + nkv + 16);
    vn[2] = *(const u16x8*)(vb + (size_t)32 * Ts + nkv);
    vn[3] = *(const u16x8*)(vb + (size_t)32 * Ts + nkv + 16);

    // S^T[kv][q] over hd=64: 4 x mfma32(K-chunk, Q-chunk)
    f32x16 s = {};
#pragma unroll
    for (int c = 0; c < 4; c++) s = mfma32(kf[c], qf[c], s);

    // scale (+ causal mask only on the diagonal tile)
    bool diag = (kv0 == q0);
    float p[16];
#pragma unroll
    for (int r = 0; r < 16; r++) {
      float v = s[r] * scale2;
      if (diag) {
        int kvl = (r & 3) + 8 * (r >> 2) + 4 * h2;
        v = (kvl > lq) ? -1e30f : v;
      }
      p[r] = v;
    }

    // per-lane scalar online softmax (lane owns one q-row; pair lane l^32 has
    // the other 16 kv -- one swap merges)
    float tmax = p[0];
#pragma unroll
    for (int r = 1; r < 16; r++) tmax = fmaxf(tmax, p[r]);
    tmax = fmaxf(tmax, __shfl_xor(tmax, 32));
    float mnew = fmaxf(mrow, tmax);
    float al = exp2f(mrow - mnew);
    mrow = mnew;
    float psum = 0.f;
#pragma unroll
    for (int r = 0; r < 16; r++) { p[r] = exp2f(p[r] - mnew); psum += p[r]; }
    psum += __shfl_xor(psum, 32);
    lsum = lsum * al + psum;
    olo *= al;
    ohi *= al;

    // in-register P -> bf16 B-fragments (T12: cvt_pk + lane-32 swap)
    unsigned w01 = cvt_pk_bf16(p[0], p[1]),   w23 = cvt_pk_bf16(p[2], p[3]);
    unsigned w45 = cvt_pk_bf16(p[4], p[5]),   w67 = cvt_pk_bf16(p[6], p[7]);
    unsigned w89 = cvt_pk_bf16(p[8], p[9]),   wAB = cvt_pk_bf16(p[10], p[11]);
    unsigned wCD = cvt_pk_bf16(p[12], p[13]), wEF = cvt_pk_bf16(p[14], p[15]);
    unsigned x01 = __shfl_xor(w01, 32), x23 = __shfl_xor(w23, 32);
    unsigned x45 = __shfl_xor(w45, 32), x67 = __shfl_xor(w67, 32);
    unsigned x89 = __shfl_xor(w89, 32), xAB = __shfl_xor(wAB, 32);
    unsigned xCD = __shfl_xor(wCD, 32), xEF = __shfl_xor(wEF, 32);
    u32x4 f0 = h2 ? (u32x4){x45, x67, w45, w67} : (u32x4){w01, w23, x01, x23};
    u32x4 f1 = h2 ? (u32x4){xCD, xEF, wCD, wEF} : (u32x4){w89, wAB, x89, xAB};
    u16x8 P0 = __builtin_bit_cast(u16x8, f0);
    u16x8 P1 = __builtin_bit_cast(u16x8, f1);

    // O^T += Vt * P^T   (lane owns q-col == softmax lane -> scalar rescale ok)
    olo = mfma32(vf[0], P0, olo);
    olo = mfma32(vf[1], P1, olo);
    ohi = mfma32(vf[2], P0, ohi);
    ohi = mfma32(vf[3], P1, ohi);

#pragma unroll
    for (int c = 0; c < 4; c++) { kf[c] = kn[c]; vf[c] = vn[c]; }
  }

  float inv = 1.0f / lsum;
  int q = q0 + lq;
  unsigned short* orow = O + ((size_t)b * Ts + q) * (size_t)(H * 64) + hh * 64;
#pragma unroll
  for (int g = 0; g < 4; g++) {
    u16x4 plo, phi;
#pragma unroll
    for (int j = 0; j < 4; j++) {
      plo[j] = f2bf(olo[g * 4 + j] * inv);   // d = j + 8g + 4h2
      phi[j] = f2bf(ohi[g * 4 + j] * inv);   // d = 32 + j + 8g + 4h2
    }
    *(u16x4*)(orow + g * 8 + h2 * 4) = plo;
    *(u16x4*)(orow + 32 + g * 8 + h2 * 4) = phi;
  }
}

// ---------- 6. upsample + residual ----------
__global__ __launch_bounds__(256) void upsample_kernel(
    const float* __restrict__ x, const float* __restrict__ proj,
    float* __restrict__ out, int T, int Ts, int D) {
  size_t g = (size_t)blockIdx.x * 256 + threadIdx.x;
  int dq = D >> 2;
  int d4 = (int)(g % dq);
  size_t bt = g / dq;
  int tt = (int)(bt % T);
  int b = (int)(bt / T);
  float src = ((float)tt + 0.5f) * ((float)Ts / (float)T) - 0.5f;
  src = fminf(fmaxf(src, 0.0f), (float)(Ts - 1));
  int i0 = (int)src;  // src >= 0 -> trunc == floor
  int i1 = min(i0 + 1, Ts - 1);
  float wg = src - (float)i0;
  const float4 xv = *(const float4*)(x + ((size_t)b * T + tt) * D + d4 * 4);
  const float4 p0 = *(const float4*)(proj + ((size_t)b * Ts + i0) * D + d4 * 4);
  const float4 p1 = *(const float4*)(proj + ((size_t)b * Ts + i1) * D + d4 * 4);
  float4 ov;
  ov.x = xv.x + p0.x * (1.0f - wg) + p1.x * wg;
  ov.y = xv.y + p0.y * (1.0f - wg) + p1.y * wg;
  ov.z = xv.z + p0.z * (1.0f - wg) + p1.z * wg;
  ov.w = xv.w + p0.w * (1.0f - wg) + p1.w * wg;
  *(float4*)(out + ((size_t)b * T + tt) * D + d4 * 4) = ov;
}

extern "C" void kernel_launch(void* const* d_in, const int* in_sizes, int n_in,
                              void* d_out, int out_size, void* d_ws, size_t ws_size,
                              hipStream_t stream) {
  (void)in_sizes; (void)n_in; (void)out_size; (void)ws_size;
  const float* x = (const float*)d_in[0];
  const float* norm_w = (const float*)d_in[1];
  const float* norm_b = (const float*)d_in[2];
  const float* W_qkv = (const float*)d_in[3];
  const float* b_qkv = (const float*)d_in[4];
  const float* W_out = (const float*)d_in[5];
  const float* b_out = (const float*)d_in[6];
  float* out = (float*)d_out;

  const int B = 4, T = 4096, D = 1024, H = 16, STR = 4;
  const int Ts = T / STR;   // 1024
  const int M = B * Ts;     // 4096

  char* ws = (char*)d_ws;
  unsigned short* xs  = (unsigned short*)(ws);                      // 8 MiB, reused as att_out
  unsigned short* Wtq = (unsigned short*)(ws + ((size_t)8 << 20));  // 6 MiB
  unsigned short* Wto = (unsigned short*)(ws + ((size_t)14 << 20)); // 2 MiB
  unsigned short* Qb  = (unsigned short*)(ws + ((size_t)16 << 20)); // 8 MiB
  unsigned short* Kb  = (unsigned short*)(ws + ((size_t)24 << 20)); // 8 MiB
  unsigned short* Vtb = (unsigned short*)(ws + ((size_t)32 << 20)); // 8 MiB
  float* proj         = (float*)(ws + ((size_t)16 << 20));          // 16 MiB, overlays Q/K (dead)
  unsigned short* att = xs;                                         // overlays xs (dead)

  ln_stride_kernel<<<M, 256, 0, stream>>>(x, norm_w, norm_b, xs, T, Ts, D, STR);
  wconv_kernel<<<dim3(3 * D / 32, D / 32), 256, 0, stream>>>(W_qkv, Wtq, D, 3 * D);
  wconv_kernel<<<dim3(D / 32, D / 32), 256, 0, stream>>>(W_out, Wto, D, D);
  gemm_kernel<0><<<(M / 128) * (3 * D / 128), 256, 0, stream>>>(
      xs, Wtq, b_qkv, M, 3 * D, D, Qb, Kb, Vtb, nullptr);
  attn_kernel<<<B * H * 8, 256, 0, stream>>>(Qb, Kb, Vtb, att, Ts, H);
  gemm_kernel<1><<<(M / 128) * (D / 128), 256, 0, stream>>>(
      att, Wto, b_out, M, D, D, nullptr, nullptr, nullptr, proj);
  upsample_kernel<<<(B * T * (D / 4)) / 256, 256, 0, stream>>>(x, proj, out, T, Ts, D);
}